// Round 6
// baseline (159.042 us; speedup 1.0000x reference)
//
#include <hip/hip_runtime.h>

// LevelLayer fully fused, one persistent kernel, 512 blocks x 512 thr
// (2 blocks/CU via ~46KB LDS + __launch_bounds__(512,4) => 16 waves/CU,
// VGPR cap 128 so the 30-row GIN gather keeps loads in flight).
// KEY CHANGE vs round 5: all FFN weights are staged into LDS ONCE per block
// (fp32-converted at staging) and read from LDS -- round 5 streamed each
// weight matrix 4-8x per block through the per-CU L1 (~3MB/CU => ~22us of
// pure L1 streaming, the measured occupancy-insensitive bottleneck).
// Phases: detect -> space FFN -> [BAR A] -> kNN -> GIN1 -> [BAR B] ->
//         GIN2 -> out FFN.  Weight staging overlaps the gather phases.
// Cross-block data (pos/hA/hB) written with AGENT-scope relaxed atomic
// stores (coherence-point, no L2 wb/inv fences needed at the barrier).
// Barrier: 32-leaf(x16) + root counter tree, spread flags, relaxed poll.
// Outputs in d_out: h[8192*64] | x_emb[8192*4] | ei[2*122880].

#define N_NODES 8192
#define NPE     256
#define KNN     15
#define LAT     64
#define HID     128
#define NK      (N_NODES*KNN)
#define NBLK    512
#define NTHR    512
#define NPB     16
#define EI0     (N_NODES*LAT + N_NODES*4)

// barrier region (zeroed by hipMemsetAsync each launch)
#define BARA_LEAF 0
#define BARA_ROOT 2048
#define BARA_FLAG 4096
#define BARB_LEAF 8192
#define BARB_ROOT 10240
#define BARB_FLAG 12288
#define BAR_BYTES 16384

#define OFF_HA  BAR_BYTES
#define OFF_HB  (OFF_HA + N_NODES*LAT*4)
#define OFF_POS (OFF_HB + N_NODES*LAT*4)

typedef unsigned short bf16;
typedef unsigned int   u32;
typedef unsigned long long u64;

__device__ __forceinline__ float bf2f(bf16 s) {
    union { u32 u; float f; } v; v.u = ((u32)s) << 16; return v.f;
}
__device__ __forceinline__ bf16 f2bf(float f) {
    union { float f; u32 u; } v; v.f = f;
    u32 u = v.u + 0x7fffu + ((v.u >> 16) & 1u);   // RNE
    return (bf16)(u >> 16);
}
__device__ __forceinline__ float ldf(const void* p, int i, int f32) {
    return f32 ? ((const float*)p)[i] : bf2f(((const bf16*)p)[i]);
}
// agent-scope relaxed atomic store: bypasses local L1/L2, completes at the
// cross-XCD coherence point. vmcnt(0) after these == globally visible.
__device__ __forceinline__ void st_coh(float* p, float v) {
    __hip_atomic_store(p, v, __ATOMIC_RELAXED, __HIP_MEMORY_SCOPE_AGENT);
}

struct KArgs {
    const void* x;
    const void* se1; const void* bse1; const void* se2; const void* bse2;
    const void* g1a; const void* bg1a; const void* g1b; const void* bg1b;
    const void* g2a; const void* bg2a; const void* g2b; const void* bg2b;
    const void* oe1; const void* boe1; const void* oe2; const void* boe2;
    const u32* wdet;                 // d_in[7] = W_g1a raw bits
    float* hA; float* hB; float* pos; int* bar;
    void* out;
};

struct Shm {
    union {                               // 33.3 KB: staged weights + bias
        float W[LAT*HID + HID];           // fp32 always (converted at staging)
        float kpos[NPE*3];
        int   red[NTHR];
    } w;
    union {                               // 4 KB
        float m[NPB*LAT];                 // GIN aggregate
        float sh[NPB*LAT];                // gin2 output -> out FFN
    } a;
    union {                               // 8 KB
        float t[NPB*HID];                 // GIN hidden
        float hid[NPB][LAT];              // space hidden
        float st[NPB*LAT];                // out hidden
    } b;
    int snb[NPB*KNN];                     // 960 B
    int flag;
};                                        // ~46.3 KB -> 2 blocks/CU

// stage nfloats to LDS as fp32 (vectorized, converts bf16 once per element)
__device__ __forceinline__ void stage(float* dst, const void* src, int nfloats,
                                      int f32, int tid) {
    if (f32) {
        const float4* s = (const float4*)src;
        float4* d = (float4*)dst;
        for (int i = tid; i < nfloats/4; i += NTHR) d[i] = s[i];
    } else {
        const ushort4* s = (const ushort4*)src;
        float4* d = (float4*)dst;
        for (int i = tid; i < nfloats/4; i += NTHR) {
            const ushort4 v = s[i];
            float4 o; o.x = bf2f(v.x); o.y = bf2f(v.y);
            o.z = bf2f(v.z); o.w = bf2f(v.w);
            d[i] = o;
        }
    }
}

// Fence-free tree grid barrier (512 arrivals: 32 leaves x 16 -> root).
// Bounded spin: broken co-residency -> clean wrong answer, never a hang.
__device__ __forceinline__ void gridbar(int* leaf, int* root, int* flags) {
    asm volatile("s_waitcnt vmcnt(0)" ::: "memory");   // all waves: stores acked
    __syncthreads();
    if (threadIdx.x == 0) {
        const int l = blockIdx.x & 31;
        if (__hip_atomic_fetch_add(leaf + l*16, 1, __ATOMIC_RELAXED,
                                   __HIP_MEMORY_SCOPE_AGENT) == 15) {
            if (__hip_atomic_fetch_add(root, 1, __ATOMIC_RELAXED,
                                       __HIP_MEMORY_SCOPE_AGENT) == 31) {
                #pragma unroll
                for (int i = 0; i < 32; i++)
                    __hip_atomic_store(flags + i*16, 1, __ATOMIC_RELAXED,
                                       __HIP_MEMORY_SCOPE_AGENT);
            }
        }
        int guard = 0;
        while (__hip_atomic_load(flags + l*16, __ATOMIC_RELAXED,
                                 __HIP_MEMORY_SCOPE_AGENT) == 0) {
            __builtin_amdgcn_s_sleep(2);
            if (++guard > (1 << 20)) break;            // fail-safe
        }
        __builtin_amdgcn_fence(__ATOMIC_ACQUIRE, "workgroup"); // compiler order
    }
    __syncthreads();
}

// GIN layer: hout = hin + mlp(hin + sum_nbr hin).  NPB=16, 512 thr.
// Staging of Wa overlaps the 32-row gather; all weight reads from LDS fp32.
// phase2: thread=(node-quad, u) 4-node reuse; phase3: thread=(node-pair, f).
template<bool LAST>
__device__ __forceinline__ void gin_layer(Shm& S, int base, int f32,
        const float* __restrict__ hin, float* hout,
        const void* Wa, const void* ba, const void* Wb, const void* bb,
        void* out)
{
    const int tid = threadIdx.x;
    // ---- stage Wa+ba  ||  phase 1 gather (disjoint LDS regions)
    stage(S.w.W, Wa, LAT*HID, f32, tid);
    stage(S.w.W + LAT*HID, ba, HID, f32, tid);
    const int n = tid >> 6, f = tid & 63;
    float own0, own1;
    {
        const int* nb0 = &S.snb[n*KNN];
        const int* nb1 = &S.snb[(n+8)*KNN];
        own0 = hin[(base+n  )*LAT + f];
        own1 = hin[(base+n+8)*LAT + f];
        float v0[KNN], v1[KNN];
        #pragma unroll
        for (int k = 0; k < KNN; k++) v0[k] = hin[nb0[k]*LAT + f];
        #pragma unroll
        for (int k = 0; k < KNN; k++) v1[k] = hin[nb1[k]*LAT + f];
        {   // tree sum, same association as previous rounds
            float s0 = v0[0]+v0[1], s1 = v0[2]+v0[3], s2 = v0[4]+v0[5];
            float s3 = v0[6]+v0[7], s4 = v0[8]+v0[9], s5 = v0[10]+v0[11];
            float s6 = v0[12]+v0[13];
            S.a.m[tid] = own0 + (((s0+s1)+(s2+s3)) + ((s4+s5)+(s6+v0[14])));
        }
        {
            float s0 = v1[0]+v1[1], s1 = v1[2]+v1[3], s2 = v1[4]+v1[5];
            float s3 = v1[6]+v1[7], s4 = v1[8]+v1[9], s5 = v1[10]+v1[11];
            float s6 = v1[12]+v1[13];
            S.a.m[tid+NTHR] = own1 + (((s0+s1)+(s2+s3)) + ((s4+s5)+(s6+v1[14])));
        }
    }
    __syncthreads();
    // ---- phase 2: t[16][128] = relu(m @ Wa + ba); thread=(g4, u), 4-node reuse
    {
        const int g4 = (tid >> 7) * 4, u = tid & 127;
        const float bias = S.w.W[LAT*HID + u];
        float a0 = bias, a1 = bias, a2 = bias, a3 = bias;
        #pragma unroll 8
        for (int ff = 0; ff < LAT; ff++) {
            const float w = S.w.W[ff*HID + u];
            a0 = fmaf(S.a.m[(g4    )*LAT + ff], w, a0);
            a1 = fmaf(S.a.m[(g4 + 1)*LAT + ff], w, a1);
            a2 = fmaf(S.a.m[(g4 + 2)*LAT + ff], w, a2);
            a3 = fmaf(S.a.m[(g4 + 3)*LAT + ff], w, a3);
        }
        S.b.t[(g4    )*HID + u] = a0 > 0.f ? a0 : 0.f;
        S.b.t[(g4 + 1)*HID + u] = a1 > 0.f ? a1 : 0.f;
        S.b.t[(g4 + 2)*HID + u] = a2 > 0.f ? a2 : 0.f;
        S.b.t[(g4 + 3)*HID + u] = a3 > 0.f ? a3 : 0.f;
    }
    __syncthreads();
    // ---- stage Wb+bb (W buffer free now)
    stage(S.w.W, Wb, HID*LAT, f32, tid);
    stage(S.w.W + HID*LAT, bb, LAT, f32, tid);
    __syncthreads();
    // ---- phase 3: g = t @ Wb + bb + own; thread=(n -> nodes n, n+8; f)
    {
        const float bias = S.w.W[HID*LAT + f];
        float a0 = bias, a1 = bias;
        #pragma unroll 8
        for (int u = 0; u < HID; u++) {
            const float w = S.w.W[u*LAT + f];
            a0 = fmaf(S.b.t[(n    )*HID + u], w, a0);
            a1 = fmaf(S.b.t[(n + 8)*HID + u], w, a1);
        }
        const float o0 = own0 + a0, o1 = own1 + a1;
        const int gi0 = base + n, gi1 = base + n + 8;
        if (!LAST) {
            st_coh(&hout[gi0*LAT + f], o0);
            st_coh(&hout[gi1*LAT + f], o1);
        } else {
            S.a.sh[(n    )*LAT + f] = o0;        // m dead -> reuse as sh
            S.a.sh[(n + 8)*LAT + f] = o1;
            if (f32) {
                ((float*)out)[gi0*LAT + f] = o0;  // output 0: final h
                ((float*)out)[gi1*LAT + f] = o1;
            } else {
                ((bf16*)out)[gi0*LAT + f] = f2bf(o0);
                ((bf16*)out)[gi1*LAT + f] = f2bf(o1);
            }
        }
    }
    __syncthreads();
}

__global__ __launch_bounds__(NTHR, 4) void k_fused(KArgs a)
{
    __shared__ Shm S;
    const int tid = threadIdx.x, blk = blockIdx.x;
    const int base = blk * NPB;

    // ---- P0: dtype detect (16 KB scan of W_g1a; L2-hot)
    {
        int c = 0;
        for (int i = tid; i < 4096; i += NTHR) {
            const u32 x = a.wdet[i];
            c += ((x >> 7)  & 0xffu) >= 0xC8u;   // low half as bf16: |v| >= 2^73
            c += ((x >> 23) & 0xffu) >= 0xC8u;   // high half
        }
        S.w.red[tid] = c;
        __syncthreads();
        for (int s = NTHR/2; s > 0; s >>= 1) {
            if (tid < s) S.w.red[tid] += S.w.red[tid + s];
            __syncthreads();
        }
        if (tid == 0) S.flag = (S.w.red[0] > 64) ? 1 : 0;   // 1 = fp32 inputs
        __syncthreads();
    }
    const int f32 = S.flag;
    __syncthreads();

    // ---- P1: space_emb  h = leaky(x@W1+b1)@W2+b2
    {
        stage(S.w.W, a.se2, LAT*LAT, f32, tid);          // || hidden GEMM
        stage(S.w.W + LAT*LAT, a.bse2, LAT, f32, tid);
        #pragma unroll
        for (int p = 0; p < 2; p++) {
            const int e = tid + p*NTHR, n = e >> 6, f = e & 63, node = base + n;
            float acc = ldf(a.bse1, f, f32);
            #pragma unroll
            for (int i = 0; i < 4; i++)
                acc = fmaf(ldf(a.x, node*4 + i, f32), ldf(a.se1, i*LAT + f, f32), acc);
            acc = acc > 0.f ? acc : 0.01f*acc;              // leaky
            S.b.hid[n][f] = acc;
        }
        __syncthreads();
        // out: thread=(n -> nodes n, n+8; f), weights from LDS
        const int n = tid >> 6, f = tid & 63;
        const float bias = S.w.W[LAT*LAT + f];
        float a0 = bias, a1 = bias;
        #pragma unroll 8
        for (int j = 0; j < LAT; j++) {
            const float w = S.w.W[j*LAT + f];
            a0 = fmaf(S.b.hid[n][j],     w, a0);
            a1 = fmaf(S.b.hid[n + 8][j], w, a1);
        }
        const int n0 = base + n, n1 = base + n + 8;
        st_coh(&a.hA[n0*LAT + f], a0);
        st_coh(&a.hA[n1*LAT + f], a1);
        if (f < 3) {
            st_coh(&a.pos[n0*3 + f], a0);
            st_coh(&a.pos[n1*3 + f], a1);
        }
    }
    gridbar(a.bar + BARA_LEAF/4, a.bar + BARA_ROOT/4, a.bar + BARA_FLAG/4);

    // ---- P2: kNN; 8 waves, 2 nodes per wave; nbr kept in LDS
    {
        const int eb = base & ~(NPE - 1);
        for (int i = tid; i < NPE*3; i += NTHR) S.w.kpos[i] = a.pos[(size_t)eb*3 + i];
        __syncthreads();
        const int wave = tid >> 6, lane = tid & 63;
        #pragma unroll
        for (int t = 0; t < 2; ++t) {
            const int n  = base + wave*2 + t;
            const int nl = n - eb;
            const float px = S.w.kpos[nl*3], py = S.w.kpos[nl*3+1], pz = S.w.kpos[nl*3+2];
            u64 key[4];
            #pragma unroll
            for (int c = 0; c < 4; c++) {
                const int j = 64*c + lane;
                const float dx = px - S.w.kpos[j*3], dy = py - S.w.kpos[j*3+1],
                            dz = pz - S.w.kpos[j*3+2];
                // match numpy fp32 ((x^2 + y^2) + z^2), contraction suppressed
                float dd = __fmul_rn(dx, dx);
                dd = __fadd_rn(dd, __fmul_rn(dy, dy));
                dd = __fadd_rn(dd, __fmul_rn(dz, dz));
                key[c] = ((u64)__float_as_uint(dd) << 32) | (u32)j;
                if (j == nl) key[c] = ~0ull;                 // exclude self
            }
            // sort 4 candidates ascending: (0,1)(2,3)(0,2)(1,3)(1,2)
            #define CSWAP(A,B) { const u64 x_ = key[A], y_ = key[B]; \
                                 key[A] = x_ < y_ ? x_ : y_; key[B] = x_ < y_ ? y_ : x_; }
            CSWAP(0,1) CSWAP(2,3) CSWAP(0,2) CSWAP(1,3) CSWAP(1,2)
            #undef CSWAP
            int myj = 0;                                     // lane k keeps k-th winner
            #pragma unroll
            for (int k = 0; k < KNN; k++) {
                u64 m = key[0];                              // lane-sorted: head is min
                #pragma unroll
                for (int s = 32; s >= 1; s >>= 1) {          // butterfly min, 64 lanes
                    const u64 o = __shfl_xor(m, s, 64);
                    m = o < m ? o : m;
                }
                if (lane == k) myj = (int)(u32)m;
                const bool hit = (key[0] == m);              // unique j => one holder
                key[0] = hit ? key[1] : key[0];              // pop
                key[1] = hit ? key[2] : key[1];
                key[2] = hit ? key[3] : key[2];
                key[3] = hit ? ~0ull  : key[3];
            }
            if (lane < KNN) {
                const int gj = eb + myj;
                S.snb[(n - base)*KNN + lane] = gj;
                if (f32) {
                    float* o = (float*)a.out;
                    o[EI0 + n*KNN + lane]      = (float)gj;  // output 2: ei
                    o[EI0 + NK + n*KNN + lane] = (float)n;
                } else {
                    bf16* o = (bf16*)a.out;
                    o[EI0 + n*KNN + lane]      = f2bf((float)gj);
                    o[EI0 + NK + n*KNN + lane] = f2bf((float)n);
                }
            }
        }
        __syncthreads();
    }

    // ---- P3: GIN layer 1 (hA -> hB, coherence-point stores)
    gin_layer<false>(S, base, f32, a.hA, a.hB,
                     a.g1a, a.bg1a, a.g1b, a.bg1b, nullptr);
    gridbar(a.bar + BARB_LEAF/4, a.bar + BARB_ROOT/4, a.bar + BARB_FLAG/4);

    // ---- P4: GIN layer 2 (hB -> LDS sh + d_out h)
    gin_layer<true>(S, base, f32, a.hB, nullptr,
                    a.g2a, a.bg2a, a.g2b, a.bg2b, a.out);

    // ---- P5: out_emb FFN from LDS sh (block-local)
    {
        stage(S.w.W, a.oe1, LAT*LAT, f32, tid);
        stage(S.w.W + LAT*LAT, a.boe1, LAT, f32, tid);
        __syncthreads();
        const int n = tid >> 6, f = tid & 63;
        const float bias = S.w.W[LAT*LAT + f];
        float a0 = bias, a1 = bias;
        #pragma unroll 8
        for (int j = 0; j < LAT; j++) {
            const float w = S.w.W[j*LAT + f];
            a0 = fmaf(S.a.sh[(n    )*LAT + j], w, a0);
            a1 = fmaf(S.a.sh[(n + 8)*LAT + j], w, a1);
        }
        a0 = a0 > 0.f ? a0 : 0.01f*a0;                      // leaky
        a1 = a1 > 0.f ? a1 : 0.01f*a1;
        S.b.st[(n    )*LAT + f] = a0;                        // t dead -> st
        S.b.st[(n + 8)*LAT + f] = a1;
        __syncthreads();
        if (tid < NPB*4) {
            const int nn = tid >> 2, ff = tid & 3;
            float acc = ldf(a.boe2, ff, f32);
            for (int j = 0; j < LAT; j++)
                acc = fmaf(S.b.st[nn*LAT + j], ldf(a.oe2, j*4 + ff, f32), acc);
            const int xo = N_NODES*LAT + (base + nn)*4 + ff; // output 1: x_emb
            if (f32) ((float*)a.out)[xo] = acc;
            else     ((bf16*)a.out)[xo] = f2bf(acc);
        }
    }
}

extern "C" void kernel_launch(void* const* d_in, const int* in_sizes, int n_in,
                              void* d_out, int out_size, void* d_ws, size_t ws_size,
                              hipStream_t stream)
{
    (void)in_sizes; (void)n_in; (void)out_size; (void)ws_size;
    char* ws = (char*)d_ws;

    KArgs a;
    a.x   = d_in[0];
    a.se1 = d_in[3];  a.bse1 = d_in[4];  a.se2 = d_in[5];  a.bse2 = d_in[6];
    a.g1a = d_in[7];  a.bg1a = d_in[8];  a.g1b = d_in[9];  a.bg1b = d_in[10];
    a.g2a = d_in[11]; a.bg2a = d_in[12]; a.g2b = d_in[13]; a.bg2b = d_in[14];
    a.oe1 = d_in[15]; a.boe1 = d_in[16]; a.oe2 = d_in[17]; a.boe2 = d_in[18];
    a.wdet = (const u32*)d_in[7];
    a.hA  = (float*)(ws + OFF_HA);
    a.hB  = (float*)(ws + OFF_HB);
    a.pos = (float*)(ws + OFF_POS);
    a.bar = (int*)ws;
    a.out = d_out;

    hipMemsetAsync(d_ws, 0, BAR_BYTES, stream);   // zero barrier tree (captured)
    k_fused<<<dim3(NBLK), dim3(NTHR), 0, stream>>>(a);
}

// Round 7
// 146.722 us; speedup vs baseline: 1.0840x; 1.0840x over previous
//
#include <hip/hip_runtime.h>

// LevelLayer fully fused, one persistent kernel, 512 blocks x 512 thr
// (2 blocks/CU via ~21KB LDS + __launch_bounds__(512,4) => 16 waves/CU).
// KEY CHANGE vs round 6: NO grid-wide barriers. All graph dependencies are
// EVENT-local (256 nodes), so the two sync points are per-event 16-arrival
// barriers. Block b handles event ev = b & 31, slice s = b >> 5 -> the 16
// blocks of an event share b%8 == ev%8, i.e. land on ONE XCD under round-
// robin dispatch => hA/hB exchange is L2-local and barrier skew is bounded
// by 16 equal blocks instead of 512-block global convergence.
// Phases: detect -> space FFN -> [EVBAR A] -> kNN -> GIN1 -> [EVBAR B] ->
//         GIN2 -> out FFN.  Weights read inline from d_in (round-4 body,
//         the best-measured variant; LDS staging measured 0% in round 6).
// Cross-block data (pos/hA/hB) written with AGENT-scope relaxed atomic
// stores (coherence-point); event barrier needs no L2 wb/inv fences.
// Outputs in d_out: h[8192*64] | x_emb[8192*4] | ei[2*122880].

#define N_NODES 8192
#define NPE     256
#define KNN     15
#define LAT     64
#define HID     128
#define NK      (N_NODES*KNN)
#define NBLK    512
#define NTHR    512
#define NPB     16
#define NEV     32
#define BPEV    16              // blocks per event
#define EI0     (N_NODES*LAT + N_NODES*4)

// barrier region (zeroed by hipMemsetAsync each launch):
// per-event counters/flags on separate 128B lines.
#define BARA_CNT 0              // + ev*128
#define BARA_FLG 4096           // + ev*128
#define BARB_CNT 8192           // + ev*128
#define BARB_FLG 12288          // + ev*128
#define BAR_BYTES 16384

#define OFF_HA  BAR_BYTES
#define OFF_HB  (OFF_HA + N_NODES*LAT*4)
#define OFF_POS (OFF_HB + N_NODES*LAT*4)

typedef unsigned short bf16;
typedef unsigned int   u32;
typedef unsigned long long u64;

__device__ __forceinline__ float bf2f(bf16 s) {
    union { u32 u; float f; } v; v.u = ((u32)s) << 16; return v.f;
}
__device__ __forceinline__ bf16 f2bf(float f) {
    union { float f; u32 u; } v; v.f = f;
    u32 u = v.u + 0x7fffu + ((v.u >> 16) & 1u);   // RNE
    return (bf16)(u >> 16);
}
__device__ __forceinline__ float ldf(const void* p, int i, int f32) {
    return f32 ? ((const float*)p)[i] : bf2f(((const bf16*)p)[i]);
}
// agent-scope relaxed atomic store: bypasses local L1/L2, completes at the
// coherence point. vmcnt(0) after these == globally visible.
__device__ __forceinline__ void st_coh(float* p, float v) {
    __hip_atomic_store(p, v, __ATOMIC_RELAXED, __HIP_MEMORY_SCOPE_AGENT);
}

struct KArgs {
    const void* x;
    const void* se1; const void* bse1; const void* se2; const void* bse2;
    const void* g1a; const void* bg1a; const void* g1b; const void* bg1b;
    const void* g2a; const void* bg2a; const void* g2b; const void* bg2b;
    const void* oe1; const void* boe1; const void* oe2; const void* boe2;
    const u32* wdet;                 // d_in[7] = W_g1a raw bits
    float* hA; float* hB; float* pos; int* bar;
    void* out;
};

struct Shm {
    union {
        int   red[NTHR];                                       // detect
        float hid[NPB][LAT];                                   // space mid
        float kpos[NPE * 3];                                   // knn
        struct { float m[NPB*LAT]; float own[NPB*LAT]; float t[NPB*HID]; } g;  // 16 KB
        float st[NPB*LAT];                                     // out mid
    } u;                                                       // 16 KB
    int   snb[NPB*KNN];
    float sh[NPB*LAT];    // gin2 output, consumed by out FFN
    int   flag;
};                        // ~21.3 KB

// Fence-free per-event barrier: 16 arrivals on one counter line, one flag
// line polled relaxed. Bounded spin: broken co-residency -> clean wrong
// answer, never a hang.
__device__ __forceinline__ void eventbar(int* cnt, int* flg) {
    asm volatile("s_waitcnt vmcnt(0)" ::: "memory");   // all waves: stores acked
    __syncthreads();
    if (threadIdx.x == 0) {
        if (__hip_atomic_fetch_add(cnt, 1, __ATOMIC_RELAXED,
                                   __HIP_MEMORY_SCOPE_AGENT) == BPEV - 1) {
            __hip_atomic_store(flg, 1, __ATOMIC_RELAXED,
                               __HIP_MEMORY_SCOPE_AGENT);
        }
        int guard = 0;
        while (__hip_atomic_load(flg, __ATOMIC_RELAXED,
                                 __HIP_MEMORY_SCOPE_AGENT) == 0) {
            __builtin_amdgcn_s_sleep(2);
            if (++guard > (1 << 20)) break;            // fail-safe
        }
        __builtin_amdgcn_fence(__ATOMIC_ACQUIRE, "workgroup"); // compiler order
    }
    __syncthreads();
}

// GIN layer: hout = hin + mlp(hin + sum_nbr hin).  NPB=16 nodes/block, 512 thr.
// phase1: 30 rows to named regs then tree-sum; phase2: (node-quad, u) 4-node
// weight reuse; phase3: (node-pair, f) 2-node reuse. (round-4 body)
template<bool LAST>
__device__ __forceinline__ void gin_layer(Shm& S, int base, int f32,
        const float* __restrict__ hin, float* hout,
        const void* Wa, const void* ba, const void* Wb, const void* bb,
        void* out)
{
    const int tid = threadIdx.x;
    // phase 1: m = own + sum of 15 neighbors (wave-uniform rows, 256B loads)
    #pragma unroll
    for (int p = 0; p < 2; p++) {
        const int e = tid + p*NTHR, n = e >> 6, f = e & 63, gi = base + n;
        const int* nb = &S.snb[n*KNN];
        const float own = hin[gi*LAT + f];
        float vv[KNN];
        #pragma unroll
        for (int k = 0; k < KNN; k++) vv[k] = hin[nb[k]*LAT + f];
        float s0 = vv[0] + vv[1],  s1 = vv[2]  + vv[3],  s2 = vv[4]  + vv[5];
        float s3 = vv[6] + vv[7],  s4 = vv[8]  + vv[9],  s5 = vv[10] + vv[11];
        float s6 = vv[12] + vv[13];
        const float acc = own + (((s0 + s1) + (s2 + s3)) + ((s4 + s5) + (s6 + vv[14])));
        S.u.g.m[e] = acc; S.u.g.own[e] = own;
    }
    __syncthreads();
    // phase 2: t[16][128] = relu(m @ Wa + ba); thread = (n4=(tid>>7)*4, u=tid&127)
    {
        const int n4 = (tid >> 7) * 4, u = tid & 127;
        float a0 = ldf(ba, u, f32);
        float a1 = a0, a2 = a0, a3 = a0;
        if (f32) {
            const float* W = (const float*)Wa;
            #pragma unroll 8
            for (int f = 0; f < LAT; f++) {
                const float w = W[f*HID + u];
                a0 = fmaf(S.u.g.m[(n4    )*LAT + f], w, a0);
                a1 = fmaf(S.u.g.m[(n4 + 1)*LAT + f], w, a1);
                a2 = fmaf(S.u.g.m[(n4 + 2)*LAT + f], w, a2);
                a3 = fmaf(S.u.g.m[(n4 + 3)*LAT + f], w, a3);
            }
        } else {
            const bf16* W = (const bf16*)Wa;
            #pragma unroll 8
            for (int f = 0; f < LAT; f++) {
                const float w = bf2f(W[f*HID + u]);
                a0 = fmaf(S.u.g.m[(n4    )*LAT + f], w, a0);
                a1 = fmaf(S.u.g.m[(n4 + 1)*LAT + f], w, a1);
                a2 = fmaf(S.u.g.m[(n4 + 2)*LAT + f], w, a2);
                a3 = fmaf(S.u.g.m[(n4 + 3)*LAT + f], w, a3);
            }
        }
        S.u.g.t[(n4    )*HID + u] = a0 > 0.f ? a0 : 0.f;
        S.u.g.t[(n4 + 1)*HID + u] = a1 > 0.f ? a1 : 0.f;
        S.u.g.t[(n4 + 2)*HID + u] = a2 > 0.f ? a2 : 0.f;
        S.u.g.t[(n4 + 3)*HID + u] = a3 > 0.f ? a3 : 0.f;
    }
    __syncthreads();
    // phase 3: g[16][64] = t @ Wb + bb; thread = (q = tid>>6 -> nodes q,q+8; f)
    {
        const int q = tid >> 6, f = tid & 63;
        float a0 = ldf(bb, f, f32);
        float a1 = a0;
        if (f32) {
            const float* W = (const float*)Wb;
            #pragma unroll 8
            for (int u = 0; u < HID; u++) {
                const float w = W[u*LAT + f];
                a0 = fmaf(S.u.g.t[(q    )*HID + u], w, a0);
                a1 = fmaf(S.u.g.t[(q + 8)*HID + u], w, a1);
            }
        } else {
            const bf16* W = (const bf16*)Wb;
            #pragma unroll 8
            for (int u = 0; u < HID; u++) {
                const float w = bf2f(W[u*LAT + f]);
                a0 = fmaf(S.u.g.t[(q    )*HID + u], w, a0);
                a1 = fmaf(S.u.g.t[(q + 8)*HID + u], w, a1);
            }
        }
        const float o0 = S.u.g.own[(q    )*LAT + f] + a0;
        const float o1 = S.u.g.own[(q + 8)*LAT + f] + a1;
        const int gi0 = base + q, gi1 = base + q + 8;
        if (!LAST) {
            st_coh(&hout[gi0*LAT + f], o0);
            st_coh(&hout[gi1*LAT + f], o1);
        } else {
            S.sh[(q    )*LAT + f] = o0;
            S.sh[(q + 8)*LAT + f] = o1;
            if (f32) {
                ((float*)out)[gi0*LAT + f] = o0;        // output 0: final h
                ((float*)out)[gi1*LAT + f] = o1;
            } else {
                ((bf16*)out)[gi0*LAT + f] = f2bf(o0);
                ((bf16*)out)[gi1*LAT + f] = f2bf(o1);
            }
        }
    }
    __syncthreads();
}

__global__ __launch_bounds__(NTHR, 4) void k_fused(KArgs a)
{
    __shared__ Shm S;
    const int tid = threadIdx.x, blk = blockIdx.x;
    const int ev   = blk & (NEV - 1);          // event id; blocks of one event
    const int slc  = blk >> 5;                 // share blk%8 -> same XCD
    const int base = ev * NPE + slc * NPB;

    // ---- P0: dtype detect (16 KB scan of W_g1a; L2-hot)
    {
        int c = 0;
        for (int i = tid; i < 4096; i += NTHR) {
            const u32 x = a.wdet[i];
            c += ((x >> 7)  & 0xffu) >= 0xC8u;   // low half as bf16: |v| >= 2^73
            c += ((x >> 23) & 0xffu) >= 0xC8u;   // high half
        }
        S.u.red[tid] = c;
        __syncthreads();
        for (int s = NTHR/2; s > 0; s >>= 1) {
            if (tid < s) S.u.red[tid] += S.u.red[tid + s];
            __syncthreads();
        }
        if (tid == 0) S.flag = (S.u.red[0] > 64) ? 1 : 0;   // 1 = fp32 inputs
        __syncthreads();
    }
    const int f32 = S.flag;
    __syncthreads();

    // ---- P1: space_emb  h = leaky(x@W1+b1)@W2+b2
    {
        #pragma unroll
        for (int p = 0; p < 2; p++) {
            const int e = tid + p*NTHR, n = e >> 6, f = e & 63, node = base + n;
            float acc = ldf(a.bse1, f, f32);
            #pragma unroll
            for (int i = 0; i < 4; i++)
                acc = fmaf(ldf(a.x, node*4 + i, f32), ldf(a.se1, i*LAT + f, f32), acc);
            acc = acc > 0.f ? acc : 0.01f*acc;              // leaky
            S.u.hid[n][f] = acc;
        }
        __syncthreads();
        // out: thread = (q -> nodes q, q+8; f). 2-node weight reuse.
        const int q = tid >> 6, f = tid & 63;
        float a0 = ldf(a.bse2, f, f32);
        float a1 = a0;
        if (f32) {
            const float* W = (const float*)a.se2;
            #pragma unroll 8
            for (int j = 0; j < LAT; j++) {
                const float w = W[j*LAT + f];
                a0 = fmaf(S.u.hid[q][j],     w, a0);
                a1 = fmaf(S.u.hid[q + 8][j], w, a1);
            }
        } else {
            const bf16* W = (const bf16*)a.se2;
            #pragma unroll 8
            for (int j = 0; j < LAT; j++) {
                const float w = bf2f(W[j*LAT + f]);
                a0 = fmaf(S.u.hid[q][j],     w, a0);
                a1 = fmaf(S.u.hid[q + 8][j], w, a1);
            }
        }
        const int n0 = base + q, n1 = base + q + 8;
        st_coh(&a.hA[n0*LAT + f], a0);
        st_coh(&a.hA[n1*LAT + f], a1);
        if (f < 3) {
            st_coh(&a.pos[n0*3 + f], a0);
            st_coh(&a.pos[n1*3 + f], a1);
        }
    }
    eventbar(a.bar + (BARA_CNT + ev*128)/4, a.bar + (BARA_FLG + ev*128)/4);

    // ---- P2: kNN; 8 waves, 2 nodes per wave; nbr kept in LDS
    {
        const int eb = ev * NPE;
        for (int i = tid; i < NPE*3; i += NTHR) S.u.kpos[i] = a.pos[(size_t)eb*3 + i];
        __syncthreads();
        const int wave = tid >> 6, lane = tid & 63;
        #pragma unroll
        for (int t = 0; t < 2; ++t) {
            const int n  = base + wave*2 + t;
            const int nl = n - eb;
            const float px = S.u.kpos[nl*3], py = S.u.kpos[nl*3+1], pz = S.u.kpos[nl*3+2];
            u64 key[4];
            #pragma unroll
            for (int c = 0; c < 4; c++) {
                const int j = 64*c + lane;
                const float dx = px - S.u.kpos[j*3], dy = py - S.u.kpos[j*3+1],
                            dz = pz - S.u.kpos[j*3+2];
                // match numpy fp32 ((x^2 + y^2) + z^2), contraction suppressed
                float dd = __fmul_rn(dx, dx);
                dd = __fadd_rn(dd, __fmul_rn(dy, dy));
                dd = __fadd_rn(dd, __fmul_rn(dz, dz));
                key[c] = ((u64)__float_as_uint(dd) << 32) | (u32)j;
                if (j == nl) key[c] = ~0ull;                 // exclude self
            }
            // sort 4 candidates ascending: (0,1)(2,3)(0,2)(1,3)(1,2)
            #define CSWAP(A,B) { const u64 x_ = key[A], y_ = key[B]; \
                                 key[A] = x_ < y_ ? x_ : y_; key[B] = x_ < y_ ? y_ : x_; }
            CSWAP(0,1) CSWAP(2,3) CSWAP(0,2) CSWAP(1,3) CSWAP(1,2)
            #undef CSWAP
            int myj = 0;                                     // lane k keeps k-th winner
            #pragma unroll
            for (int k = 0; k < KNN; k++) {
                u64 m = key[0];                              // lane-sorted: head is min
                #pragma unroll
                for (int s = 32; s >= 1; s >>= 1) {          // butterfly min, 64 lanes
                    const u64 o = __shfl_xor(m, s, 64);
                    m = o < m ? o : m;
                }
                if (lane == k) myj = (int)(u32)m;
                const bool hit = (key[0] == m);              // unique j => one holder
                key[0] = hit ? key[1] : key[0];              // pop
                key[1] = hit ? key[2] : key[1];
                key[2] = hit ? key[3] : key[2];
                key[3] = hit ? ~0ull  : key[3];
            }
            if (lane < KNN) {
                const int gj = eb + myj;
                S.snb[(n - base)*KNN + lane] = gj;
                if (f32) {
                    float* o = (float*)a.out;
                    o[EI0 + n*KNN + lane]      = (float)gj;  // output 2: ei
                    o[EI0 + NK + n*KNN + lane] = (float)n;
                } else {
                    bf16* o = (bf16*)a.out;
                    o[EI0 + n*KNN + lane]      = f2bf((float)gj);
                    o[EI0 + NK + n*KNN + lane] = f2bf((float)n);
                }
            }
        }
        __syncthreads();
    }

    // ---- P3: GIN layer 1 (hA -> hB, coherence-point stores)
    gin_layer<false>(S, base, f32, a.hA, a.hB,
                     a.g1a, a.bg1a, a.g1b, a.bg1b, nullptr);
    eventbar(a.bar + (BARB_CNT + ev*128)/4, a.bar + (BARB_FLG + ev*128)/4);

    // ---- P4: GIN layer 2 (hB -> LDS sh + d_out h)
    gin_layer<true>(S, base, f32, a.hB, nullptr,
                    a.g2a, a.bg2a, a.g2b, a.bg2b, a.out);

    // ---- P5: out_emb FFN from LDS sh (block-local)
    {
        const int q = tid >> 6, f = tid & 63;
        float a0 = ldf(a.boe1, f, f32);
        float a1 = a0;
        if (f32) {
            const float* W = (const float*)a.oe1;
            #pragma unroll 8
            for (int j = 0; j < LAT; j++) {
                const float w = W[j*LAT + f];
                a0 = fmaf(S.sh[(q    )*LAT + j], w, a0);
                a1 = fmaf(S.sh[(q + 8)*LAT + j], w, a1);
            }
        } else {
            const bf16* W = (const bf16*)a.oe1;
            #pragma unroll 8
            for (int j = 0; j < LAT; j++) {
                const float w = bf2f(W[j*LAT + f]);
                a0 = fmaf(S.sh[(q    )*LAT + j], w, a0);
                a1 = fmaf(S.sh[(q + 8)*LAT + j], w, a1);
            }
        }
        a0 = a0 > 0.f ? a0 : 0.01f*a0;                      // leaky
        a1 = a1 > 0.f ? a1 : 0.01f*a1;
        __syncthreads();                                     // S.u reuse (st)
        S.u.st[(q    )*LAT + f] = a0;
        S.u.st[(q + 8)*LAT + f] = a1;
        __syncthreads();
        if (tid < NPB*4) {
            const int n = tid >> 2, ff = tid & 3;
            float acc = ldf(a.boe2, ff, f32);
            for (int j = 0; j < LAT; j++)
                acc = fmaf(S.u.st[n*LAT + j], ldf(a.oe2, j*4 + ff, f32), acc);
            const int xo = N_NODES*LAT + (base + n)*4 + ff;  // output 1: x_emb
            if (f32) ((float*)a.out)[xo] = acc;
            else     ((bf16*)a.out)[xo] = f2bf(acc);
        }
    }
}

extern "C" void kernel_launch(void* const* d_in, const int* in_sizes, int n_in,
                              void* d_out, int out_size, void* d_ws, size_t ws_size,
                              hipStream_t stream)
{
    (void)in_sizes; (void)n_in; (void)out_size; (void)ws_size;
    char* ws = (char*)d_ws;

    KArgs a;
    a.x   = d_in[0];
    a.se1 = d_in[3];  a.bse1 = d_in[4];  a.se2 = d_in[5];  a.bse2 = d_in[6];
    a.g1a = d_in[7];  a.bg1a = d_in[8];  a.g1b = d_in[9];  a.bg1b = d_in[10];
    a.g2a = d_in[11]; a.bg2a = d_in[12]; a.g2b = d_in[13]; a.bg2b = d_in[14];
    a.oe1 = d_in[15]; a.boe1 = d_in[16]; a.oe2 = d_in[17]; a.boe2 = d_in[18];
    a.wdet = (const u32*)d_in[7];
    a.hA  = (float*)(ws + OFF_HA);
    a.hB  = (float*)(ws + OFF_HB);
    a.pos = (float*)(ws + OFF_POS);
    a.bar = (int*)ws;
    a.out = d_out;

    hipMemsetAsync(d_ws, 0, BAR_BYTES, stream);   // zero event barriers (captured)
    k_fused<<<dim3(NBLK), dim3(NTHR), 0, stream>>>(a);
}

// Round 8
// 132.602 us; speedup vs baseline: 1.1994x; 1.1065x over previous
//
#include <hip/hip_runtime.h>

// LevelLayer fully fused, one persistent kernel, 512 blocks x 512 thr
// (2 blocks/CU via ~31KB LDS + __launch_bounds__(512,4) => 16 waves/CU).
// ROUND 8 KEY CHANGE: GIN MLPs run on the MATRIX pipe.
//   Instruction audit showed the two GIN layers = 67% of all VALU
//   instructions at ~0.35 MAC/inst; MfmaUtil was 0.0 (matrix pipe idle).
//   phase2: [16 nodes x 64] @ Wa[64 x 128]  -> 8 waves x 1 N-tile, K=2 steps
//   phase3: [16 x 128] @ Wb[128 x 64]       -> 4 waves x 1 N-tile, K=4 steps
//   via v_mfma_f32_16x16x32_bf16. fp32 accuracy kept by exact hi/lo bf16
//   split of activations (A = Ahi + Alo): bf16-weight case: 2 MFMAs
//   (Ahi@B + Alo@B, B exact); fp32-weight case: 3 MFMAs (drop Alo@Blo term
//   ~2^-16). Gather vectorized to float4 (8 loads/thread vs 32 scalar).
// Everything else = round 7: event-local 16-arrival barriers (FETCH_SIZE
// 15->3MB), agent-scope coherence stores, same kNN.
// Outputs in d_out: h[8192*64] | x_emb[8192*4] | ei[2*122880].

#define N_NODES 8192
#define NPE     256
#define KNN     15
#define LAT     64
#define HID     128
#define NK      (N_NODES*KNN)
#define NBLK    512
#define NTHR    512
#define NPB     16
#define NEV     32
#define BPEV    16
#define EI0     (N_NODES*LAT + N_NODES*4)
#define PADM    68              // m tile leading dim (fp32), breaks bank stride
#define PADT    136             // t tile leading dim (bf16)

// barrier region (zeroed by hipMemsetAsync each launch)
#define BARA_CNT 0              // + ev*128
#define BARA_FLG 4096
#define BARB_CNT 8192
#define BARB_FLG 12288
#define BAR_BYTES 16384

#define OFF_HA  BAR_BYTES
#define OFF_HB  (OFF_HA + N_NODES*LAT*4)
#define OFF_POS (OFF_HB + N_NODES*LAT*4)

typedef unsigned short bf16;
typedef unsigned int   u32;
typedef unsigned long long u64;
typedef short s16x8 __attribute__((ext_vector_type(8)));
typedef float f32x4 __attribute__((ext_vector_type(4)));

__device__ __forceinline__ float bf2f(bf16 s) {
    union { u32 u; float f; } v; v.u = ((u32)s) << 16; return v.f;
}
__device__ __forceinline__ bf16 f2bf(float f) {
    union { float f; u32 u; } v; v.f = f;
    u32 u = v.u + 0x7fffu + ((v.u >> 16) & 1u);   // RNE
    return (bf16)(u >> 16);
}
__device__ __forceinline__ float ldf(const void* p, int i, int f32) {
    return f32 ? ((const float*)p)[i] : bf2f(((const bf16*)p)[i]);
}
__device__ __forceinline__ void st_coh(float* p, float v) {
    __hip_atomic_store(p, v, __ATOMIC_RELAXED, __HIP_MEMORY_SCOPE_AGENT);
}

// ---- MFMA fragment helpers --------------------------------------------------
union Frag { u32 w[4]; s16x8 v; };

__device__ __forceinline__ u32 cvtpk(float a, float b) {   // lo=bf16(a), hi=bf16(b)
    u32 r; asm("v_cvt_pk_bf16_f32 %0, %1, %2" : "=v"(r) : "v"(a), "v"(b));
    return r;
}
__device__ __forceinline__ float lo2f(u32 w) { union {u32 u; float f;} v; v.u = w << 16;          return v.f; }
__device__ __forceinline__ float hi2f(u32 w) { union {u32 u; float f;} v; v.u = w & 0xffff0000u;  return v.f; }

// exact split: x == bf16hi + bf16lo to ~2^-16 relative
__device__ __forceinline__ void split8(const float* x, Frag& hi, Frag& lo) {
    #pragma unroll
    for (int i = 0; i < 4; i++) {
        hi.w[i] = cvtpk(x[2*i], x[2*i+1]);
        lo.w[i] = cvtpk(x[2*i]   - lo2f(hi.w[i]),
                        x[2*i+1] - hi2f(hi.w[i]));
    }
}
// A-frag (fp32 row in LDS, 8 consecutive K): row = lane&15, k0 = (lane>>4)*8
__device__ __forceinline__ void packA(const float* p, Frag& hi, Frag& lo) {
    float xv[8];
    *(float4*)&xv[0] = *(const float4*)p;
    *(float4*)&xv[4] = *(const float4*)(p + 4);
    split8(xv, hi, lo);
}
// B-frag bf16 weights (exact): col = lane&15, rows k0..k0+7 stride = ncols
__device__ __forceinline__ void loadB_bf(const bf16* p, int stride, Frag& f) {
    #pragma unroll
    for (int i = 0; i < 4; i++)
        f.w[i] = (u32)p[(2*i)*stride] | ((u32)p[(2*i+1)*stride] << 16);
}
__device__ __forceinline__ void loadB_f32(const float* p, int stride, Frag& hi, Frag& lo) {
    float xv[8];
    #pragma unroll
    for (int j = 0; j < 8; j++) xv[j] = p[j*stride];
    split8(xv, hi, lo);
}
__device__ __forceinline__ f32x4 MF(const Frag& a, const Frag& b, f32x4 c) {
    return __builtin_amdgcn_mfma_f32_16x16x32_bf16(a.v, b.v, c, 0, 0, 0);
}

struct KArgs {
    const void* x;
    const void* se1; const void* bse1; const void* se2; const void* bse2;
    const void* g1a; const void* bg1a; const void* g1b; const void* bg1b;
    const void* g2a; const void* bg2a; const void* g2b; const void* bg2b;
    const void* oe1; const void* boe1; const void* oe2; const void* boe2;
    const u32* wdet;
    float* hA; float* hB; float* pos; int* bar;
    void* out;
};

struct Shm {
    union {
        int    red[NTHR];                                  // detect (2 KB)
        float  hid[NPB][LAT];                              // space mid (4 KB)
        struct { float x[NPE], y[NPE], z[NPE]; } k;        // knn SoA (3 KB)
        float4 part[2][NPB][16];                           // gather partials (8 KB)
        float  st[NPB*LAT];                                // out mid (4 KB)
    } u;                                                   // 8 KB
    float m[NPB*PADM];                                     // 4.25 KB (padded)
    float own[NPB*LAT];                                    // 4 KB
    struct { bf16 hi[NPB*PADT]; bf16 lo[NPB*PADT]; } t;    // 8.5 KB (padded)
    float sh[NPB*LAT];                                     // 4 KB
    int   snb[NPB*KNN];                                    // 960 B
    int   flag;
};                                                         // ~31 KB

// Fence-free per-event barrier (16 arrivals). Bounded spin.
__device__ __forceinline__ void eventbar(int* cnt, int* flg) {
    asm volatile("s_waitcnt vmcnt(0)" ::: "memory");
    __syncthreads();
    if (threadIdx.x == 0) {
        if (__hip_atomic_fetch_add(cnt, 1, __ATOMIC_RELAXED,
                                   __HIP_MEMORY_SCOPE_AGENT) == BPEV - 1) {
            __hip_atomic_store(flg, 1, __ATOMIC_RELAXED,
                               __HIP_MEMORY_SCOPE_AGENT);
        }
        int guard = 0;
        while (__hip_atomic_load(flg, __ATOMIC_RELAXED,
                                 __HIP_MEMORY_SCOPE_AGENT) == 0) {
            __builtin_amdgcn_s_sleep(2);
            if (++guard > (1 << 20)) break;
        }
        __builtin_amdgcn_fence(__ATOMIC_ACQUIRE, "workgroup");
    }
    __syncthreads();
}

// GIN layer via MFMA: hout = hin + mlp(hin + sum_nbr hin). 16 nodes/block.
template<bool LAST>
__device__ __forceinline__ void gin_layer(Shm& S, int base, int f32,
        const float* __restrict__ hin, float* hout,
        const void* Wa, const void* ba, const void* Wb, const void* bb,
        void* out)
{
    const int tid = threadIdx.x;
    const int lane = tid & 63, wv = tid >> 6;
    const int ln15 = lane & 15, kg = lane >> 4;            // MFMA lane coords

    // ---- gather: m[16][64] = own + sum 15 nbrs, float4-vectorized.
    // thread = (half h, node n, f4-slot): 8 float4 loads each.
    {
        const int h = tid >> 8, n = (tid >> 4) & 15, slot = tid & 15;
        const float4* h4 = (const float4*)hin;
        const int* nb = &S.snb[n*KNN];
        float4 s4;
        if (h == 0) {
            s4 = h4[(size_t)(base + n)*16 + slot];          // own row
            *(float4*)&S.own[n*LAT + slot*4] = s4;
            #pragma unroll
            for (int k = 0; k < 7; k++) {
                const float4 v = h4[(size_t)nb[k]*16 + slot];
                s4.x += v.x; s4.y += v.y; s4.z += v.z; s4.w += v.w;
            }
        } else {
            s4 = h4[(size_t)nb[7]*16 + slot];
            #pragma unroll
            for (int k = 8; k < 15; k++) {
                const float4 v = h4[(size_t)nb[k]*16 + slot];
                s4.x += v.x; s4.y += v.y; s4.z += v.z; s4.w += v.w;
            }
        }
        S.u.part[h][n][slot] = s4;
        __syncthreads();
        if (tid < 256) {
            const int n2 = tid >> 4, sl = tid & 15;
            const float4 p0 = S.u.part[0][n2][sl], p1 = S.u.part[1][n2][sl];
            float4 mm; mm.x = p0.x + p1.x; mm.y = p0.y + p1.y;
            mm.z = p0.z + p1.z; mm.w = p0.w + p1.w;
            *(float4*)&S.m[n2*PADM + sl*4] = mm;
        }
        __syncthreads();
    }

    // ---- phase 2 (MFMA): t[16][128] = relu(m @ Wa + ba); wave = N-tile u0
    {
        const int u0 = wv * 16;
        const float bias = ldf(ba, u0 + ln15, f32);
        f32x4 acc; acc[0] = bias; acc[1] = bias; acc[2] = bias; acc[3] = bias;
        Frag a0h, a0l, a1h, a1l;
        packA(&S.m[ln15*PADM +  0 + kg*8], a0h, a0l);      // K-step 0
        packA(&S.m[ln15*PADM + 32 + kg*8], a1h, a1l);      // K-step 1
        if (f32) {
            const float* W = (const float*)Wa;
            Frag b0h, b0l, b1h, b1l;
            loadB_f32(W + ( 0 + kg*8)*HID + u0 + ln15, HID, b0h, b0l);
            loadB_f32(W + (32 + kg*8)*HID + u0 + ln15, HID, b1h, b1l);
            acc = MF(a0h, b0h, acc); acc = MF(a0l, b0h, acc); acc = MF(a0h, b0l, acc);
            acc = MF(a1h, b1h, acc); acc = MF(a1l, b1h, acc); acc = MF(a1h, b1l, acc);
        } else {
            const bf16* W = (const bf16*)Wa;
            Frag b0, b1;
            loadB_bf(W + ( 0 + kg*8)*HID + u0 + ln15, HID, b0);
            loadB_bf(W + (32 + kg*8)*HID + u0 + ln15, HID, b1);
            acc = MF(a0h, b0, acc); acc = MF(a0l, b0, acc);
            acc = MF(a1h, b1, acc); acc = MF(a1l, b1, acc);
        }
        // epilogue: relu, split to hi/lo bf16, store t (C row = kg*4+r, col=ln15)
        #pragma unroll
        for (int r = 0; r < 4; r++) {
            const int row = kg*4 + r;
            float v = acc[r]; v = v > 0.f ? v : 0.f;
            const bf16 h = f2bf(v);
            S.t.hi[row*PADT + u0 + ln15] = h;
            S.t.lo[row*PADT + u0 + ln15] = f2bf(v - bf2f(h));
        }
    }
    __syncthreads();

    // ---- phase 3 (MFMA, waves 0-3): g[16][64] = t @ Wb + bb + own
    if (wv < 4) {
        const int f0 = wv * 16;
        const float bias = ldf(bb, f0 + ln15, f32);
        f32x4 acc; acc[0] = bias; acc[1] = bias; acc[2] = bias; acc[3] = bias;
        #pragma unroll
        for (int s = 0; s < 4; s++) {
            Frag ah, al;
            ah.v = *(const s16x8*)&S.t.hi[ln15*PADT + s*32 + kg*8];
            al.v = *(const s16x8*)&S.t.lo[ln15*PADT + s*32 + kg*8];
            if (f32) {
                const float* W = (const float*)Wb;
                Frag bh, bl;
                loadB_f32(W + (s*32 + kg*8)*LAT + f0 + ln15, LAT, bh, bl);
                acc = MF(ah, bh, acc); acc = MF(al, bh, acc); acc = MF(ah, bl, acc);
            } else {
                const bf16* W = (const bf16*)Wb;
                Frag b;
                loadB_bf(W + (s*32 + kg*8)*LAT + f0 + ln15, LAT, b);
                acc = MF(ah, b, acc); acc = MF(al, b, acc);
            }
        }
        #pragma unroll
        for (int r = 0; r < 4; r++) {
            const int row = kg*4 + r, f = f0 + ln15, gi = base + row;
            const float o = acc[r] + S.own[row*LAT + f];
            if (!LAST) {
                st_coh(&hout[gi*LAT + f], o);
            } else {
                S.sh[row*LAT + f] = o;
                if (f32) ((float*)out)[gi*LAT + f] = o;     // output 0: final h
                else     ((bf16*)out)[gi*LAT + f] = f2bf(o);
            }
        }
    }
    __syncthreads();
}

__global__ __launch_bounds__(NTHR, 4) void k_fused(KArgs a)
{
    __shared__ Shm S;
    const int tid = threadIdx.x, blk = blockIdx.x;
    const int ev   = blk & (NEV - 1);
    const int slc  = blk >> 5;
    const int base = ev * NPE + slc * NPB;

    // ---- P0: dtype detect
    {
        int c = 0;
        for (int i = tid; i < 4096; i += NTHR) {
            const u32 x = a.wdet[i];
            c += ((x >> 7)  & 0xffu) >= 0xC8u;
            c += ((x >> 23) & 0xffu) >= 0xC8u;
        }
        S.u.red[tid] = c;
        __syncthreads();
        for (int s = NTHR/2; s > 0; s >>= 1) {
            if (tid < s) S.u.red[tid] += S.u.red[tid + s];
            __syncthreads();
        }
        if (tid == 0) S.flag = (S.u.red[0] > 64) ? 1 : 0;
        __syncthreads();
    }
    const int f32 = S.flag;
    __syncthreads();

    // ---- P1: space_emb  h = leaky(x@W1+b1)@W2+b2  (round-7 body)
    {
        #pragma unroll
        for (int p = 0; p < 2; p++) {
            const int e = tid + p*NTHR, n = e >> 6, f = e & 63, node = base + n;
            float acc = ldf(a.bse1, f, f32);
            #pragma unroll
            for (int i = 0; i < 4; i++)
                acc = fmaf(ldf(a.x, node*4 + i, f32), ldf(a.se1, i*LAT + f, f32), acc);
            acc = acc > 0.f ? acc : 0.01f*acc;
            S.u.hid[n][f] = acc;
        }
        __syncthreads();
        const int q = tid >> 6, f = tid & 63;
        float a0 = ldf(a.bse2, f, f32);
        float a1 = a0;
        if (f32) {
            const float* W = (const float*)a.se2;
            #pragma unroll 8
            for (int j = 0; j < LAT; j++) {
                const float w = W[j*LAT + f];
                a0 = fmaf(S.u.hid[q][j],     w, a0);
                a1 = fmaf(S.u.hid[q + 8][j], w, a1);
            }
        } else {
            const bf16* W = (const bf16*)a.se2;
            #pragma unroll 8
            for (int j = 0; j < LAT; j++) {
                const float w = bf2f(W[j*LAT + f]);
                a0 = fmaf(S.u.hid[q][j],     w, a0);
                a1 = fmaf(S.u.hid[q + 8][j], w, a1);
            }
        }
        const int n0 = base + q, n1 = base + q + 8;
        st_coh(&a.hA[n0*LAT + f], a0);
        st_coh(&a.hA[n1*LAT + f], a1);
        if (f < 3) {
            st_coh(&a.pos[n0*3 + f], a0);
            st_coh(&a.pos[n1*3 + f], a1);
        }
    }
    eventbar(a.bar + (BARA_CNT + ev*128)/4, a.bar + (BARA_FLG + ev*128)/4);

    // ---- P2: kNN (round-7 algorithm, SoA pos in LDS)
    {
        const int eb = ev * NPE;
        if (tid < NPE) {
            S.u.k.x[tid] = a.pos[(size_t)(eb + tid)*3 + 0];
            S.u.k.y[tid] = a.pos[(size_t)(eb + tid)*3 + 1];
            S.u.k.z[tid] = a.pos[(size_t)(eb + tid)*3 + 2];
        }
        __syncthreads();
        const int wave = tid >> 6, lane = tid & 63;
        #pragma unroll
        for (int t = 0; t < 2; ++t) {
            const int n  = base + wave*2 + t;
            const int nl = n - eb;
            const float px = S.u.k.x[nl], py = S.u.k.y[nl], pz = S.u.k.z[nl];
            u64 key[4];
            #pragma unroll
            for (int c = 0; c < 4; c++) {
                const int j = 64*c + lane;
                const float dx = px - S.u.k.x[j], dy = py - S.u.k.y[j],
                            dz = pz - S.u.k.z[j];
                float dd = __fmul_rn(dx, dx);
                dd = __fadd_rn(dd, __fmul_rn(dy, dy));
                dd = __fadd_rn(dd, __fmul_rn(dz, dz));
                key[c] = ((u64)__float_as_uint(dd) << 32) | (u32)j;
                if (j == nl) key[c] = ~0ull;
            }
            #define CSWAP(A,B) { const u64 x_ = key[A], y_ = key[B]; \
                                 key[A] = x_ < y_ ? x_ : y_; key[B] = x_ < y_ ? y_ : x_; }
            CSWAP(0,1) CSWAP(2,3) CSWAP(0,2) CSWAP(1,3) CSWAP(1,2)
            #undef CSWAP
            int myj = 0;
            #pragma unroll
            for (int k = 0; k < KNN; k++) {
                u64 m = key[0];
                #pragma unroll
                for (int s = 32; s >= 1; s >>= 1) {
                    const u64 o = __shfl_xor(m, s, 64);
                    m = o < m ? o : m;
                }
                if (lane == k) myj = (int)(u32)m;
                const bool hit = (key[0] == m);
                key[0] = hit ? key[1] : key[0];
                key[1] = hit ? key[2] : key[1];
                key[2] = hit ? key[3] : key[2];
                key[3] = hit ? ~0ull  : key[3];
            }
            if (lane < KNN) {
                const int gj = eb + myj;
                S.snb[(n - base)*KNN + lane] = gj;
                if (f32) {
                    float* o = (float*)a.out;
                    o[EI0 + n*KNN + lane]      = (float)gj;
                    o[EI0 + NK + n*KNN + lane] = (float)n;
                } else {
                    bf16* o = (bf16*)a.out;
                    o[EI0 + n*KNN + lane]      = f2bf((float)gj);
                    o[EI0 + NK + n*KNN + lane] = f2bf((float)n);
                }
            }
        }
        __syncthreads();
    }

    // ---- P3: GIN layer 1 (MFMA, hA -> hB)
    gin_layer<false>(S, base, f32, a.hA, a.hB,
                     a.g1a, a.bg1a, a.g1b, a.bg1b, nullptr);
    eventbar(a.bar + (BARB_CNT + ev*128)/4, a.bar + (BARB_FLG + ev*128)/4);

    // ---- P4: GIN layer 2 (MFMA, hB -> sh + d_out h)
    gin_layer<true>(S, base, f32, a.hB, nullptr,
                    a.g2a, a.bg2a, a.g2b, a.bg2b, a.out);

    // ---- P5: out_emb FFN from LDS sh (round-7 body)
    {
        const int q = tid >> 6, f = tid & 63;
        float a0 = ldf(a.boe1, f, f32);
        float a1 = a0;
        if (f32) {
            const float* W = (const float*)a.oe1;
            #pragma unroll 8
            for (int j = 0; j < LAT; j++) {
                const float w = W[j*LAT + f];
                a0 = fmaf(S.sh[(q    )*LAT + j], w, a0);
                a1 = fmaf(S.sh[(q + 8)*LAT + j], w, a1);
            }
        } else {
            const bf16* W = (const bf16*)a.oe1;
            #pragma unroll 8
            for (int j = 0; j < LAT; j++) {
                const float w = bf2f(W[j*LAT + f]);
                a0 = fmaf(S.sh[(q    )*LAT + j], w, a0);
                a1 = fmaf(S.sh[(q + 8)*LAT + j], w, a1);
            }
        }
        a0 = a0 > 0.f ? a0 : 0.01f*a0;
        a1 = a1 > 0.f ? a1 : 0.01f*a1;
        __syncthreads();
        S.u.st[(q    )*LAT + f] = a0;
        S.u.st[(q + 8)*LAT + f] = a1;
        __syncthreads();
        if (tid < NPB*4) {
            const int n = tid >> 2, ff = tid & 3;
            float acc = ldf(a.boe2, ff, f32);
            for (int j = 0; j < LAT; j++)
                acc = fmaf(S.u.st[n*LAT + j], ldf(a.oe2, j*4 + ff, f32), acc);
            const int xo = N_NODES*LAT + (base + n)*4 + ff;
            if (f32) ((float*)a.out)[xo] = acc;
            else     ((bf16*)a.out)[xo] = f2bf(acc);
        }
    }
}

extern "C" void kernel_launch(void* const* d_in, const int* in_sizes, int n_in,
                              void* d_out, int out_size, void* d_ws, size_t ws_size,
                              hipStream_t stream)
{
    (void)in_sizes; (void)n_in; (void)out_size; (void)ws_size;
    char* ws = (char*)d_ws;

    KArgs a;
    a.x   = d_in[0];
    a.se1 = d_in[3];  a.bse1 = d_in[4];  a.se2 = d_in[5];  a.bse2 = d_in[6];
    a.g1a = d_in[7];  a.bg1a = d_in[8];  a.g1b = d_in[9];  a.bg1b = d_in[10];
    a.g2a = d_in[11]; a.bg2a = d_in[12]; a.g2b = d_in[13]; a.bg2b = d_in[14];
    a.oe1 = d_in[15]; a.boe1 = d_in[16]; a.oe2 = d_in[17]; a.boe2 = d_in[18];
    a.wdet = (const u32*)d_in[7];
    a.hA  = (float*)(ws + OFF_HA);
    a.hB  = (float*)(ws + OFF_HB);
    a.pos = (float*)(ws + OFF_POS);
    a.bar = (int*)ws;
    a.out = d_out;

    hipMemsetAsync(d_ws, 0, BAR_BYTES, stream);
    k_fused<<<dim3(NBLK), dim3(NTHR), 0, stream>>>(a);
}

// Round 9
// 131.706 us; speedup vs baseline: 1.2076x; 1.0068x over previous
//
#include <hip/hip_runtime.h>

// LevelLayer fully fused, one persistent kernel, 512 blocks x 512 thr.
// ROUND 9: finish moving matmuls to the matrix pipe + cut serial chains.
//  - space-p2 and out-p1 now MFMA (16x64 @ 64x64, 4 waves, K=2 steps,
//    exact hi/lo bf16 split). pos (h[:,:3] -> kNN -> ei) is computed by 48
//    spare threads with the BIT-IDENTICAL fp32 fmaf chain of rounds 3-8, so
//    graph topology numerics are unchanged.
//  - kNN: both nodes of a wave computed together; the two butterfly-min
//    chains interleave in one k-loop (ILP on the longest serial chain).
//  - GIN gather single-stage (thread=(node, float2-slot), 16 loads), no
//    LDS partials, -2 syncthreads per layer.
//  - detect via wave shfl-reduce (2 barriers); vector x loads; s_sleep(1).
// Structure from round 7/8: event-local 16-arrival barriers, agent-scope
// coherence stores, MFMA GIN layers.
// Outputs in d_out: h[8192*64] | x_emb[8192*4] | ei[2*122880].

#define N_NODES 8192
#define NPE     256
#define KNN     15
#define LAT     64
#define HID     128
#define NK      (N_NODES*KNN)
#define NBLK    512
#define NTHR    512
#define NPB     16
#define NEV     32
#define BPEV    16
#define EI0     (N_NODES*LAT + N_NODES*4)
#define PADM    68              // fp32 tile leading dims (bank-conflict pad)
#define PADH    68
#define PADT    136             // bf16 tile leading dim

#define BARA_CNT 0              // + ev*128
#define BARA_FLG 4096
#define BARB_CNT 8192
#define BARB_FLG 12288
#define BAR_BYTES 16384

#define OFF_HA  BAR_BYTES
#define OFF_HB  (OFF_HA + N_NODES*LAT*4)
#define OFF_POS (OFF_HB + N_NODES*LAT*4)

typedef unsigned short bf16;
typedef unsigned int   u32;
typedef unsigned long long u64;
typedef short s16x8 __attribute__((ext_vector_type(8)));
typedef float f32x4 __attribute__((ext_vector_type(4)));

__device__ __forceinline__ float bf2f(bf16 s) {
    union { u32 u; float f; } v; v.u = ((u32)s) << 16; return v.f;
}
__device__ __forceinline__ bf16 f2bf(float f) {
    union { float f; u32 u; } v; v.f = f;
    u32 u = v.u + 0x7fffu + ((v.u >> 16) & 1u);   // RNE
    return (bf16)(u >> 16);
}
__device__ __forceinline__ float ldf(const void* p, int i, int f32) {
    return f32 ? ((const float*)p)[i] : bf2f(((const bf16*)p)[i]);
}
__device__ __forceinline__ void st_coh(float* p, float v) {
    __hip_atomic_store(p, v, __ATOMIC_RELAXED, __HIP_MEMORY_SCOPE_AGENT);
}

// ---- MFMA fragment helpers --------------------------------------------------
union Frag { u32 w[4]; s16x8 v; };

__device__ __forceinline__ u32 cvtpk(float a, float b) {   // lo=bf16(a), hi=bf16(b)
    u32 r; asm("v_cvt_pk_bf16_f32 %0, %1, %2" : "=v"(r) : "v"(a), "v"(b));
    return r;
}
__device__ __forceinline__ float lo2f(u32 w) { union {u32 u; float f;} v; v.u = w << 16;         return v.f; }
__device__ __forceinline__ float hi2f(u32 w) { union {u32 u; float f;} v; v.u = w & 0xffff0000u; return v.f; }

__device__ __forceinline__ void split8(const float* x, Frag& hi, Frag& lo) {
    #pragma unroll
    for (int i = 0; i < 4; i++) {
        hi.w[i] = cvtpk(x[2*i], x[2*i+1]);
        lo.w[i] = cvtpk(x[2*i]   - lo2f(hi.w[i]),
                        x[2*i+1] - hi2f(hi.w[i]));
    }
}
__device__ __forceinline__ void packA(const float* p, Frag& hi, Frag& lo) {
    float xv[8];
    *(float4*)&xv[0] = *(const float4*)p;
    *(float4*)&xv[4] = *(const float4*)(p + 4);
    split8(xv, hi, lo);
}
__device__ __forceinline__ void loadB_bf(const bf16* p, int stride, Frag& f) {
    #pragma unroll
    for (int i = 0; i < 4; i++)
        f.w[i] = (u32)p[(2*i)*stride] | ((u32)p[(2*i+1)*stride] << 16);
}
__device__ __forceinline__ void loadB_f32(const float* p, int stride, Frag& hi, Frag& lo) {
    float xv[8];
    #pragma unroll
    for (int j = 0; j < 8; j++) xv[j] = p[j*stride];
    split8(xv, hi, lo);
}
__device__ __forceinline__ f32x4 MF(const Frag& a, const Frag& b, f32x4 c) {
    return __builtin_amdgcn_mfma_f32_16x16x32_bf16(a.v, b.v, c, 0, 0, 0);
}

struct KArgs {
    const void* x;
    const void* se1; const void* bse1; const void* se2; const void* bse2;
    const void* g1a; const void* bg1a; const void* g1b; const void* bg1b;
    const void* g2a; const void* bg2a; const void* g2b; const void* bg2b;
    const void* oe1; const void* boe1; const void* oe2; const void* boe2;
    const u32* wdet;
    float* hA; float* hB; float* pos; int* bar;
    void* out;
};

struct Shm {
    union {
        int   red[8];                                      // detect wave partials
        float hid[NPB][PADH];                              // space mid (padded)
        struct { float x[NPE], y[NPE], z[NPE]; } k;        // knn SoA
        float st[NPB*LAT];                                 // out mid
    } u;                                                   // 4.4 KB
    float m[NPB*PADM];                                     // 4.35 KB
    float own[NPB*LAT];                                    // 4 KB
    struct { bf16 hi[NPB*PADT]; bf16 lo[NPB*PADT]; } t;    // 8.7 KB
    float sh[NPB*PADH];                                    // 4.35 KB
    int   snb[NPB*KNN];                                    // 960 B
    int   flag;
};                                                         // ~27 KB

// Fence-free per-event barrier (16 arrivals). Bounded spin.
__device__ __forceinline__ void eventbar(int* cnt, int* flg) {
    asm volatile("s_waitcnt vmcnt(0)" ::: "memory");
    __syncthreads();
    if (threadIdx.x == 0) {
        if (__hip_atomic_fetch_add(cnt, 1, __ATOMIC_RELAXED,
                                   __HIP_MEMORY_SCOPE_AGENT) == BPEV - 1) {
            __hip_atomic_store(flg, 1, __ATOMIC_RELAXED,
                               __HIP_MEMORY_SCOPE_AGENT);
        }
        int guard = 0;
        while (__hip_atomic_load(flg, __ATOMIC_RELAXED,
                                 __HIP_MEMORY_SCOPE_AGENT) == 0) {
            __builtin_amdgcn_s_sleep(1);
            if (++guard > (1 << 21)) break;
        }
        __builtin_amdgcn_fence(__ATOMIC_ACQUIRE, "workgroup");
    }
    __syncthreads();
}

// GIN layer via MFMA. 16 nodes/block, 512 thr.
template<bool LAST>
__device__ __forceinline__ void gin_layer(Shm& S, int base, int f32,
        const float* __restrict__ hin, float* hout,
        const void* Wa, const void* ba, const void* Wb, const void* bb,
        void* out)
{
    const int tid = threadIdx.x;
    const int lane = tid & 63, wv = tid >> 6;
    const int ln15 = lane & 15, kg = lane >> 4;

    // ---- gather (single stage): thread = (node n, float2 slot sl)
    {
        const int n = tid >> 5, sl = tid & 31;
        const float2* h2 = (const float2*)hin;
        const int* nb = &S.snb[n*KNN];
        const float2 o = h2[(size_t)(base + n)*32 + sl];
        *(float2*)&S.own[n*LAT + sl*2] = o;
        float2 vv[KNN];
        #pragma unroll
        for (int k = 0; k < KNN; k++) vv[k] = h2[(size_t)nb[k]*32 + sl];
        float2 mm;
        {
            float s0 = vv[0].x+vv[1].x, s1 = vv[2].x+vv[3].x, s2 = vv[4].x+vv[5].x;
            float s3 = vv[6].x+vv[7].x, s4 = vv[8].x+vv[9].x, s5 = vv[10].x+vv[11].x;
            float s6 = vv[12].x+vv[13].x;
            mm.x = o.x + (((s0+s1)+(s2+s3)) + ((s4+s5)+(s6+vv[14].x)));
        }
        {
            float s0 = vv[0].y+vv[1].y, s1 = vv[2].y+vv[3].y, s2 = vv[4].y+vv[5].y;
            float s3 = vv[6].y+vv[7].y, s4 = vv[8].y+vv[9].y, s5 = vv[10].y+vv[11].y;
            float s6 = vv[12].y+vv[13].y;
            mm.y = o.y + (((s0+s1)+(s2+s3)) + ((s4+s5)+(s6+vv[14].y)));
        }
        *(float2*)&S.m[n*PADM + sl*2] = mm;
        __syncthreads();
    }

    // ---- phase 2 (MFMA): t[16][128] = relu(m @ Wa + ba); 8 waves x N-tile
    {
        const int u0 = wv * 16;
        const float bias = ldf(ba, u0 + ln15, f32);
        f32x4 acc; acc[0] = bias; acc[1] = bias; acc[2] = bias; acc[3] = bias;
        Frag a0h, a0l, a1h, a1l;
        packA(&S.m[ln15*PADM +  0 + kg*8], a0h, a0l);
        packA(&S.m[ln15*PADM + 32 + kg*8], a1h, a1l);
        if (f32) {
            const float* W = (const float*)Wa;
            Frag b0h, b0l, b1h, b1l;
            loadB_f32(W + ( 0 + kg*8)*HID + u0 + ln15, HID, b0h, b0l);
            loadB_f32(W + (32 + kg*8)*HID + u0 + ln15, HID, b1h, b1l);
            acc = MF(a0h, b0h, acc); acc = MF(a0l, b0h, acc); acc = MF(a0h, b0l, acc);
            acc = MF(a1h, b1h, acc); acc = MF(a1l, b1h, acc); acc = MF(a1h, b1l, acc);
        } else {
            const bf16* W = (const bf16*)Wa;
            Frag b0, b1;
            loadB_bf(W + ( 0 + kg*8)*HID + u0 + ln15, HID, b0);
            loadB_bf(W + (32 + kg*8)*HID + u0 + ln15, HID, b1);
            acc = MF(a0h, b0, acc); acc = MF(a0l, b0, acc);
            acc = MF(a1h, b1, acc); acc = MF(a1l, b1, acc);
        }
        #pragma unroll
        for (int r = 0; r < 4; r++) {
            const int row = kg*4 + r;
            float v = acc[r]; v = v > 0.f ? v : 0.f;
            const bf16 h = f2bf(v);
            S.t.hi[row*PADT + u0 + ln15] = h;
            S.t.lo[row*PADT + u0 + ln15] = f2bf(v - bf2f(h));
        }
    }
    __syncthreads();

    // ---- phase 3 (MFMA, waves 0-3): g[16][64] = t @ Wb + bb + own
    if (wv < 4) {
        const int f0 = wv * 16;
        const float bias = ldf(bb, f0 + ln15, f32);
        f32x4 acc; acc[0] = bias; acc[1] = bias; acc[2] = bias; acc[3] = bias;
        #pragma unroll
        for (int s = 0; s < 4; s++) {
            Frag ah, al;
            ah.v = *(const s16x8*)&S.t.hi[ln15*PADT + s*32 + kg*8];
            al.v = *(const s16x8*)&S.t.lo[ln15*PADT + s*32 + kg*8];
            if (f32) {
                const float* W = (const float*)Wb;
                Frag bh, bl;
                loadB_f32(W + (s*32 + kg*8)*LAT + f0 + ln15, LAT, bh, bl);
                acc = MF(ah, bh, acc); acc = MF(al, bh, acc); acc = MF(ah, bl, acc);
            } else {
                const bf16* W = (const bf16*)Wb;
                Frag b;
                loadB_bf(W + (s*32 + kg*8)*LAT + f0 + ln15, LAT, b);
                acc = MF(ah, b, acc); acc = MF(al, b, acc);
            }
        }
        #pragma unroll
        for (int r = 0; r < 4; r++) {
            const int row = kg*4 + r, f = f0 + ln15, gi = base + row;
            const float o = acc[r] + S.own[row*LAT + f];
            if (!LAST) {
                st_coh(&hout[gi*LAT + f], o);
            } else {
                S.sh[row*PADH + f] = o;
                if (f32) ((float*)out)[gi*LAT + f] = o;     // output 0: final h
                else     ((bf16*)out)[gi*LAT + f] = f2bf(o);
            }
        }
    }
    __syncthreads();
}

__global__ __launch_bounds__(NTHR, 4) void k_fused(KArgs a)
{
    __shared__ Shm S;
    const int tid = threadIdx.x, blk = blockIdx.x;
    const int lane = tid & 63, wv = tid >> 6;
    const int ln15 = lane & 15, kg = lane >> 4;
    const int ev   = blk & (NEV - 1);
    const int slc  = blk >> 5;
    const int base = ev * NPE + slc * NPB;

    // ---- P0: dtype detect (16 KB scan; wave shfl-reduce, 2 barriers)
    {
        int c = 0;
        for (int i = tid; i < 4096; i += NTHR) {
            const u32 x = a.wdet[i];
            c += ((x >> 7)  & 0xffu) >= 0xC8u;
            c += ((x >> 23) & 0xffu) >= 0xC8u;
        }
        #pragma unroll
        for (int s = 32; s >= 1; s >>= 1) c += __shfl_xor(c, s, 64);
        if (lane == 0) S.u.red[wv] = c;
        __syncthreads();
        if (tid == 0) {
            int t = 0;
            #pragma unroll
            for (int i = 0; i < 8; i++) t += S.u.red[i];
            S.flag = (t > 64) ? 1 : 0;
        }
        __syncthreads();
    }
    const int f32 = S.flag;
    __syncthreads();

    // ---- P1: space_emb  h = leaky(x@W1+b1)@W2+b2
    {
        #pragma unroll
        for (int p = 0; p < 2; p++) {
            const int e = tid + p*NTHR, n = e >> 6, f = e & 63, node = base + n;
            float xr[4];
            if (f32) {
                const float4 x4 = ((const float4*)a.x)[node];
                xr[0] = x4.x; xr[1] = x4.y; xr[2] = x4.z; xr[3] = x4.w;
            } else {
                const ushort4 x4 = ((const ushort4*)a.x)[node];
                xr[0] = bf2f(x4.x); xr[1] = bf2f(x4.y);
                xr[2] = bf2f(x4.z); xr[3] = bf2f(x4.w);
            }
            float acc = ldf(a.bse1, f, f32);
            #pragma unroll
            for (int i = 0; i < 4; i++)
                acc = fmaf(xr[i], ldf(a.se1, i*LAT + f, f32), acc);
            acc = acc > 0.f ? acc : 0.01f*acc;              // leaky
            S.u.hid[n][f] = acc;
        }
        __syncthreads();
        // p2a (waves 0-3, MFMA): hA[16][64] = hid @ W2 + b2
        if (wv < 4) {
            const int f0 = wv * 16;
            const float bias = ldf(a.bse2, f0 + ln15, f32);
            f32x4 acc; acc[0] = bias; acc[1] = bias; acc[2] = bias; acc[3] = bias;
            Frag a0h, a0l, a1h, a1l;
            packA(&S.u.hid[ln15][ 0 + kg*8], a0h, a0l);
            packA(&S.u.hid[ln15][32 + kg*8], a1h, a1l);
            if (f32) {
                const float* W = (const float*)a.se2;
                Frag b0h, b0l, b1h, b1l;
                loadB_f32(W + ( 0 + kg*8)*LAT + f0 + ln15, LAT, b0h, b0l);
                loadB_f32(W + (32 + kg*8)*LAT + f0 + ln15, LAT, b1h, b1l);
                acc = MF(a0h, b0h, acc); acc = MF(a0l, b0h, acc); acc = MF(a0h, b0l, acc);
                acc = MF(a1h, b1h, acc); acc = MF(a1l, b1h, acc); acc = MF(a1h, b1l, acc);
            } else {
                const bf16* W = (const bf16*)a.se2;
                Frag b0, b1;
                loadB_bf(W + ( 0 + kg*8)*LAT + f0 + ln15, LAT, b0);
                loadB_bf(W + (32 + kg*8)*LAT + f0 + ln15, LAT, b1);
                acc = MF(a0h, b0, acc); acc = MF(a0l, b0, acc);
                acc = MF(a1h, b1, acc); acc = MF(a1l, b1, acc);
            }
            #pragma unroll
            for (int r = 0; r < 4; r++) {
                const int row = kg*4 + r;
                st_coh(&a.hA[(base + row)*LAT + f0 + ln15], acc[r]);
            }
        } else if (tid - 256 < 48) {
            // p2b: EXACT pos (3 cols) -- bit-identical fmaf chain (rounds 3-8)
            const int idx = tid - 256, n = idx / 3, f = idx % 3;
            float acc = ldf(a.bse2, f, f32);
            if (f32) {
                const float* W = (const float*)a.se2;
                #pragma unroll 8
                for (int j = 0; j < LAT; j++)
                    acc = fmaf(S.u.hid[n][j], W[j*LAT + f], acc);
            } else {
                const bf16* W = (const bf16*)a.se2;
                #pragma unroll 8
                for (int j = 0; j < LAT; j++)
                    acc = fmaf(S.u.hid[n][j], bf2f(W[j*LAT + f]), acc);
            }
            st_coh(&a.pos[(base + n)*3 + f], acc);
        }
    }
    eventbar(a.bar + (BARA_CNT + ev*128)/4, a.bar + (BARA_FLG + ev*128)/4);

    // ---- P2: kNN; 8 waves x 2 nodes, butterfly chains interleaved
    {
        const int eb = ev * NPE;
        if (tid < NPE) {
            S.u.k.x[tid] = a.pos[(size_t)(eb + tid)*3 + 0];
            S.u.k.y[tid] = a.pos[(size_t)(eb + tid)*3 + 1];
            S.u.k.z[tid] = a.pos[(size_t)(eb + tid)*3 + 2];
        }
        __syncthreads();
        const int n0 = base + wv*2, n1 = n0 + 1;
        const int nl0 = n0 - eb, nl1 = n1 - eb;
        const float px0 = S.u.k.x[nl0], py0 = S.u.k.y[nl0], pz0 = S.u.k.z[nl0];
        const float px1 = S.u.k.x[nl1], py1 = S.u.k.y[nl1], pz1 = S.u.k.z[nl1];
        u64 key0[4], key1[4];
        #pragma unroll
        for (int c = 0; c < 4; c++) {
            const int j = 64*c + lane;
            const float qx = S.u.k.x[j], qy = S.u.k.y[j], qz = S.u.k.z[j];
            {
                const float dx = px0 - qx, dy = py0 - qy, dz = pz0 - qz;
                float dd = __fmul_rn(dx, dx);
                dd = __fadd_rn(dd, __fmul_rn(dy, dy));
                dd = __fadd_rn(dd, __fmul_rn(dz, dz));
                key0[c] = ((u64)__float_as_uint(dd) << 32) | (u32)j;
                if (j == nl0) key0[c] = ~0ull;
            }
            {
                const float dx = px1 - qx, dy = py1 - qy, dz = pz1 - qz;
                float dd = __fmul_rn(dx, dx);
                dd = __fadd_rn(dd, __fmul_rn(dy, dy));
                dd = __fadd_rn(dd, __fmul_rn(dz, dz));
                key1[c] = ((u64)__float_as_uint(dd) << 32) | (u32)j;
                if (j == nl1) key1[c] = ~0ull;
            }
        }
        #define CSWAP(K,A,B) { const u64 x_ = K[A], y_ = K[B]; \
                               K[A] = x_ < y_ ? x_ : y_; K[B] = x_ < y_ ? y_ : x_; }
        CSWAP(key0,0,1) CSWAP(key0,2,3) CSWAP(key0,0,2) CSWAP(key0,1,3) CSWAP(key0,1,2)
        CSWAP(key1,0,1) CSWAP(key1,2,3) CSWAP(key1,0,2) CSWAP(key1,1,3) CSWAP(key1,1,2)
        #undef CSWAP
        int myj0 = 0, myj1 = 0;
        #pragma unroll
        for (int k = 0; k < KNN; k++) {
            u64 m0 = key0[0], m1 = key1[0];
            #pragma unroll
            for (int s = 32; s >= 1; s >>= 1) {     // two independent chains
                const u64 o0 = __shfl_xor(m0, s, 64);
                const u64 o1 = __shfl_xor(m1, s, 64);
                m0 = o0 < m0 ? o0 : m0;
                m1 = o1 < m1 ? o1 : m1;
            }
            if (lane == k) { myj0 = (int)(u32)m0; myj1 = (int)(u32)m1; }
            const bool h0 = (key0[0] == m0);
            key0[0] = h0 ? key0[1] : key0[0];
            key0[1] = h0 ? key0[2] : key0[1];
            key0[2] = h0 ? key0[3] : key0[2];
            key0[3] = h0 ? ~0ull   : key0[3];
            const bool h1 = (key1[0] == m1);
            key1[0] = h1 ? key1[1] : key1[0];
            key1[1] = h1 ? key1[2] : key1[1];
            key1[2] = h1 ? key1[3] : key1[2];
            key1[3] = h1 ? ~0ull   : key1[3];
        }
        if (lane < KNN) {
            const int gj0 = eb + myj0, gj1 = eb + myj1;
            S.snb[(n0 - base)*KNN + lane] = gj0;
            S.snb[(n1 - base)*KNN + lane] = gj1;
            if (f32) {
                float* o = (float*)a.out;
                o[EI0 + n0*KNN + lane]      = (float)gj0;
                o[EI0 + NK + n0*KNN + lane] = (float)n0;
                o[EI0 + n1*KNN + lane]      = (float)gj1;
                o[EI0 + NK + n1*KNN + lane] = (float)n1;
            } else {
                bf16* o = (bf16*)a.out;
                o[EI0 + n0*KNN + lane]      = f2bf((float)gj0);
                o[EI0 + NK + n0*KNN + lane] = f2bf((float)n0);
                o[EI0 + n1*KNN + lane]      = f2bf((float)gj1);
                o[EI0 + NK + n1*KNN + lane] = f2bf((float)n1);
            }
        }
        __syncthreads();
    }

    // ---- P3: GIN layer 1 (MFMA, hA -> hB)
    gin_layer<false>(S, base, f32, a.hA, a.hB,
                     a.g1a, a.bg1a, a.g1b, a.bg1b, nullptr);
    eventbar(a.bar + (BARB_CNT + ev*128)/4, a.bar + (BARB_FLG + ev*128)/4);

    // ---- P4: GIN layer 2 (MFMA, hB -> sh + d_out h)
    gin_layer<true>(S, base, f32, a.hB, nullptr,
                    a.g2a, a.bg2a, a.g2b, a.bg2b, a.out);

    // ---- P5: out_emb FFN
    {
        // p1 (waves 0-3, MFMA): st[16][64] = leaky(sh @ oe1 + boe1)
        if (wv < 4) {
            const int f0 = wv * 16;
            const float bias = ldf(a.boe1, f0 + ln15, f32);
            f32x4 acc; acc[0] = bias; acc[1] = bias; acc[2] = bias; acc[3] = bias;
            Frag a0h, a0l, a1h, a1l;
            packA(&S.sh[ln15*PADH +  0 + kg*8], a0h, a0l);
            packA(&S.sh[ln15*PADH + 32 + kg*8], a1h, a1l);
            if (f32) {
                const float* W = (const float*)a.oe1;
                Frag b0h, b0l, b1h, b1l;
                loadB_f32(W + ( 0 + kg*8)*LAT + f0 + ln15, LAT, b0h, b0l);
                loadB_f32(W + (32 + kg*8)*LAT + f0 + ln15, LAT, b1h, b1l);
                acc = MF(a0h, b0h, acc); acc = MF(a0l, b0h, acc); acc = MF(a0h, b0l, acc);
                acc = MF(a1h, b1h, acc); acc = MF(a1l, b1h, acc); acc = MF(a1h, b1l, acc);
            } else {
                const bf16* W = (const bf16*)a.oe1;
                Frag b0, b1;
                loadB_bf(W + ( 0 + kg*8)*LAT + f0 + ln15, LAT, b0);
                loadB_bf(W + (32 + kg*8)*LAT + f0 + ln15, LAT, b1);
                acc = MF(a0h, b0, acc); acc = MF(a0l, b0, acc);
                acc = MF(a1h, b1, acc); acc = MF(a1l, b1, acc);
            }
            #pragma unroll
            for (int r = 0; r < 4; r++) {
                const int row = kg*4 + r;
                float v = acc[r];
                v = v > 0.f ? v : 0.01f*v;                  // leaky
                S.u.st[row*LAT + f0 + ln15] = v;
            }
        }
        __syncthreads();
        // p2: x_emb = st @ oe2 + boe2 (64 dots of length 64)
        if (tid < NPB*4) {
            const int n = tid >> 2, ff = tid & 3;
            float acc = ldf(a.boe2, ff, f32);
            for (int j = 0; j < LAT; j++)
                acc = fmaf(S.u.st[n*LAT + j], ldf(a.oe2, j*4 + ff, f32), acc);
            const int xo = N_NODES*LAT + (base + n)*4 + ff;
            if (f32) ((float*)a.out)[xo] = acc;
            else     ((bf16*)a.out)[xo] = f2bf(acc);
        }
    }
}

extern "C" void kernel_launch(void* const* d_in, const int* in_sizes, int n_in,
                              void* d_out, int out_size, void* d_ws, size_t ws_size,
                              hipStream_t stream)
{
    (void)in_sizes; (void)n_in; (void)out_size; (void)ws_size;
    char* ws = (char*)d_ws;

    KArgs a;
    a.x   = d_in[0];
    a.se1 = d_in[3];  a.bse1 = d_in[4];  a.se2 = d_in[5];  a.bse2 = d_in[6];
    a.g1a = d_in[7];  a.bg1a = d_in[8];  a.g1b = d_in[9];  a.bg1b = d_in[10];
    a.g2a = d_in[11]; a.bg2a = d_in[12]; a.g2b = d_in[13]; a.bg2b = d_in[14];
    a.oe1 = d_in[15]; a.boe1 = d_in[16]; a.oe2 = d_in[17]; a.boe2 = d_in[18];
    a.wdet = (const u32*)d_in[7];
    a.hA  = (float*)(ws + OFF_HA);
    a.hB  = (float*)(ws + OFF_HB);
    a.pos = (float*)(ws + OFF_POS);
    a.bar = (int*)ws;
    a.out = d_out;

    hipMemsetAsync(d_ws, 0, BAR_BYTES, stream);
    k_fused<<<dim3(NBLK), dim3(NTHR), 0, stream>>>(a);
}